// Round 1
// baseline (11960.010 us; speedup 1.0000x reference)
//
#include <hip/hip_runtime.h>
#include <cstddef>

#define TM 64
#define TN 64
#define TK 32

// Generic 64x64-tile fp32 GEMM: Out[m][n] = sum_k A[m][k] * B(k,n)
//   B_K_MAJOR=false: Bm is N x Kd row-major (NT form, contract over columns of both)
//   B_K_MAJOR=true : Bm is Kd x N row-major (NN form)
// EPI: 0 = plain store; 1 = fused ISTA update:
//   Out = soft_threshold(Rold - 0.2*acc + 0.2*Cimg, 0.005)
template<bool B_K_MAJOR, int EPI>
__global__ __launch_bounds__(256)
void gemm64(const float* __restrict__ A, int lda,
            const float* __restrict__ Bm, int ldb,
            float* __restrict__ Out, int ldo,
            const float* __restrict__ Rold,
            const float* __restrict__ Cimg,
            int Kd)
{
    __shared__ float As[TK][TM];   // As[kk][row]  (transposed so reads are float4)
    __shared__ float Bs[TK][TN];   // Bs[kk][col]

    const int tid = threadIdx.x;        // 0..255
    const int tx  = tid & 15;           // 0..15 (col group)
    const int ty  = tid >> 4;           // 0..15 (row group)
    const int row0 = blockIdx.y * TM;
    const int col0 = blockIdx.x * TN;

    float acc[4][4] = {};

    for (int k0 = 0; k0 < Kd; k0 += TK) {
        // ---- stage A tile (64 rows x 32 k), transposed into LDS ----
        #pragma unroll
        for (int i = 0; i < 2; ++i) {
            int f  = tid + i * 256;         // 0..511 float4 slots
            int r  = f >> 3;                // row 0..63
            int c4 = (f & 7) << 2;          // k offset 0,4,...,28
            float4 v = *reinterpret_cast<const float4*>(
                &A[(size_t)(row0 + r) * lda + k0 + c4]);
            As[c4 + 0][r] = v.x; As[c4 + 1][r] = v.y;
            As[c4 + 2][r] = v.z; As[c4 + 3][r] = v.w;
        }
        // ---- stage B tile ----
        if (!B_K_MAJOR) {
            // Bm: N x Kd row-major; Bs[kk][n] = Bm[col0+n][k0+kk]
            #pragma unroll
            for (int i = 0; i < 2; ++i) {
                int f  = tid + i * 256;
                int r  = f >> 3;            // n 0..63
                int c4 = (f & 7) << 2;
                float4 v = *reinterpret_cast<const float4*>(
                    &Bm[(size_t)(col0 + r) * ldb + k0 + c4]);
                Bs[c4 + 0][r] = v.x; Bs[c4 + 1][r] = v.y;
                Bs[c4 + 2][r] = v.z; Bs[c4 + 3][r] = v.w;
            }
        } else {
            // Bm: Kd x N row-major; Bs[kk][n] = Bm[k0+kk][col0+n]  (direct, vectorized)
            #pragma unroll
            for (int i = 0; i < 2; ++i) {
                int f  = tid + i * 256;
                int kk = f >> 4;            // 0..31
                int n4 = (f & 15) << 2;     // 0..60
                *reinterpret_cast<float4*>(&Bs[kk][n4]) =
                    *reinterpret_cast<const float4*>(
                        &Bm[(size_t)(k0 + kk) * ldb + col0 + n4]);
            }
        }
        __syncthreads();

        // ---- inner product: 2 x ds_read_b128 + 16 v_fmac per kk ----
        #pragma unroll
        for (int kk = 0; kk < TK; ++kk) {
            float4 av = *reinterpret_cast<const float4*>(&As[kk][ty << 2]);
            float4 bv = *reinterpret_cast<const float4*>(&Bs[kk][tx << 2]);
            float a4[4] = {av.x, av.y, av.z, av.w};
            float b4[4] = {bv.x, bv.y, bv.z, bv.w};
            #pragma unroll
            for (int i2 = 0; i2 < 4; ++i2)
                #pragma unroll
                for (int j2 = 0; j2 < 4; ++j2)
                    acc[i2][j2] = fmaf(a4[i2], b4[j2], acc[i2][j2]);
        }
        __syncthreads();
    }

    // ---- epilogue ----
    #pragma unroll
    for (int i2 = 0; i2 < 4; ++i2) {
        int r = row0 + (ty << 2) + i2;
        #pragma unroll
        for (int j2 = 0; j2 < 4; ++j2) {
            int c = col0 + (tx << 2) + j2;
            size_t idx = (size_t)r * ldo + c;
            if (EPI == 0) {
                Out[idx] = acc[i2][j2];
            } else {
                float x  = Rold[idx] - 0.2f * acc[i2][j2] + 0.2f * Cimg[idx];
                float ax = fabsf(x) - 0.005f;
                Out[idx] = ax > 0.0f ? copysignf(ax, x) : 0.0f;
            }
        }
    }
}

extern "C" void kernel_launch(void* const* d_in, const int* in_sizes, int n_in,
                              void* d_out, int out_size, void* d_ws, size_t ws_size,
                              hipStream_t stream) {
    const float* img = (const float*)d_in[0];   // (2048, 1024) fp32
    const float* U   = (const float*)d_in[1];   // (1024, 1024) fp32, rows normalized
    float* out = (float*)d_out;                 // (2048, 1024) fp32

    const int B  = 2048;
    const int K  = 1024;
    const int M2 = 1024;
    const int EPOCHS = 150;

    char* ws = (char*)d_ws;
    float* G    = (float*)(ws);                                 //  4 MB: U @ U^T (K x K)
    float* Cimg = (float*)(ws + (size_t)4  * 1024 * 1024);      //  8 MB: img @ U^T (B x K)
    float* Ra   = (float*)(ws + (size_t)12 * 1024 * 1024);      //  8 MB
    float* Rb   = (float*)(ws + (size_t)20 * 1024 * 1024);      //  8 MB

    hipMemsetAsync(Ra, 0, (size_t)B * K * sizeof(float), stream);

    dim3 blk(256);

    // G = U @ U^T   (NT: contract over columns of both)
    gemm64<false, 0><<<dim3(K / TN, K / TM), blk, 0, stream>>>(
        U, M2, U, M2, G, K, nullptr, nullptr, M2);

    // Cimg = img @ U^T
    gemm64<false, 0><<<dim3(K / TN, B / TM), blk, 0, stream>>>(
        img, M2, U, M2, Cimg, K, nullptr, nullptr, M2);

    // 150 ISTA iterations: Rnext = st(R - 0.2*(R@G) + 0.2*Cimg, 0.005)
    // G is symmetric, so R@G == R@G^T -> NT form with B=G.
    float* cur = Ra;
    float* nxt = Rb;
    for (int it = 0; it < EPOCHS; ++it) {
        gemm64<false, 1><<<dim3(K / TN, B / TM), blk, 0, stream>>>(
            cur, K, G, K, nxt, K, cur, Cimg, K);
        float* t = cur; cur = nxt; nxt = t;
    }

    // out = R @ U   (NN: U is K x M2 row-major)
    gemm64<true, 0><<<dim3(M2 / TN, B / TM), blk, 0, stream>>>(
        cur, K, U, M2, out, M2, nullptr, nullptr, K);
}

// Round 2
// 7654.681 us; speedup vs baseline: 1.5624x; 1.5624x over previous
//
#include <hip/hip_runtime.h>
#include <cstddef>
#include <cstdint>

using f32x16  = __attribute__((ext_vector_type(16))) float;
using bf16x8  = __attribute__((ext_vector_type(8)))  short;
using ushort8 = __attribute__((ext_vector_type(8)))  unsigned short;

#define LMDA 0.005f

__device__ __forceinline__ unsigned short f2bf(float f) {
    union { float f; uint32_t u; } v; v.f = f;
    uint32_t u = v.u;
    return (unsigned short)((u + 0x7FFFu + ((u >> 16) & 1u)) >> 16);
}
__device__ __forceinline__ float bf2f(unsigned short b) {
    union { uint32_t u; float f; } v; v.u = ((uint32_t)b) << 16;
    return v.f;
}
__device__ __forceinline__ void split2(float x, unsigned short& h, unsigned short& l) {
    h = f2bf(x);
    l = f2bf(x - bf2f(h));
}

// ---------------------------------------------------------------------------
// Split-bf16 NT GEMM: Out[m][n] = sum_k A[m][k] * B[n][k], with
// A ~ Ahi+Alo, B ~ Bhi+Blo (bf16 pairs). acc = hi*hi + hi*lo + lo*hi (fp32).
// Tile 64x64, 4 waves (2x2), wave = one 32x32 mfma_f32_32x32x16_bf16 frag,
// BK=32 (2 k-halves of 16). LDS is fragment-ordered: every ds access is a
// conflict-free b128 at lane*16.
// EPI: 0 = store fp32 acc           (final  out = R@U)
//      1 = store fp32 0.2*acc       (c = 0.2 * img@U^T)
//      2 = split(I - 0.2*acc)       (W = I - 0.2*U@U^T)
//      3 = split(st(acc + Cs, L))   (ISTA step)
// ---------------------------------------------------------------------------
template<int EPI>
__global__ __launch_bounds__(256)
void gemm_sp(const unsigned short* __restrict__ Ahi, const unsigned short* __restrict__ Alo, int lda,
             const unsigned short* __restrict__ Bhi, const unsigned short* __restrict__ Blo, int ldb,
             int Kd, int nbx,
             unsigned short* __restrict__ OutHi, unsigned short* __restrict__ OutLo,
             float* __restrict__ OutF, const float* __restrict__ Cs, int ldo)
{
    __shared__ __align__(16) unsigned short Asm[8 * 512];  // [h*2+kh][rb] chunks, 1KB each
    __shared__ __align__(16) unsigned short Bsm[8 * 512];

    // XCD-aware bijective swizzle (all grids are multiples of 8)
    const int nwg = gridDim.x;
    const int fid = blockIdx.x;
    const int q   = nwg >> 3;
    const int sid = (fid & 7) * q + (fid >> 3);
    const int col0 = (sid % nbx) * 64;
    const int row0 = (sid / nbx) * 64;

    const int tid  = threadIdx.x;
    const int lane = tid & 63;
    const int w    = tid >> 6;     // wave 0..3
    const int wr   = w >> 1;       // wave row 0..1
    const int wc   = w & 1;        // wave col 0..1
    const int l31  = lane & 31;
    const int l5   = lane >> 5;    // 0..1

    const unsigned short* Ap[2] = {Ahi, Alo};
    const unsigned short* Bp[2] = {Bhi, Blo};

    f32x16 acc = {};

    for (int k0 = 0; k0 < Kd; k0 += 32) {
        // ---- stage: 16 chunks of 1KB, 4 per wave; lane writes its 16B ----
        #pragma unroll
        for (int t = 0; t < 4; ++t) {
            const int cid  = (w << 2) + t;     // 0..15
            const int mat  = cid >> 3;         // 0:A 1:B
            const int rest = cid & 7;          // (h*2+kh)*2 + rb
            const int h    = rest >> 2;
            const int kh   = (rest >> 1) & 1;
            const int rb   = rest & 1;
            const int row  = (rb << 5) + l31;
            const int kk   = (kh << 4) + (l5 << 3);
            const unsigned short* src = (mat ? Bp[h] : Ap[h]) +
                (size_t)((mat ? col0 : row0) + row) * (size_t)(mat ? ldb : lda) + k0 + kk;
            unsigned short* dst = (mat ? Bsm : Asm) + rest * 512 + lane * 8;
            *(ushort8*)dst = *(const ushort8*)src;
        }
        __syncthreads();

        // ---- fragments: lane's 16B at chunk base + lane*16 ----
        bf16x8 a[2][2], b[2][2];
        #pragma unroll
        for (int h = 0; h < 2; ++h) {
            #pragma unroll
            for (int kh = 0; kh < 2; ++kh) {
                a[h][kh] = *(const bf16x8*)&Asm[(((h << 1) + kh) * 2 + wr) * 512 + lane * 8];
                b[h][kh] = *(const bf16x8*)&Bsm[(((h << 1) + kh) * 2 + wc) * 512 + lane * 8];
            }
        }

        #pragma unroll
        for (int kh = 0; kh < 2; ++kh) {
            acc = __builtin_amdgcn_mfma_f32_32x32x16_bf16(a[0][kh], b[0][kh], acc, 0, 0, 0);
            acc = __builtin_amdgcn_mfma_f32_32x32x16_bf16(a[0][kh], b[1][kh], acc, 0, 0, 0);
            acc = __builtin_amdgcn_mfma_f32_32x32x16_bf16(a[1][kh], b[0][kh], acc, 0, 0, 0);
        }
        __syncthreads();
    }

    // ---- epilogue: C/D layout col=lane&31, row=(r&3)+8*(r>>2)+4*(lane>>5) ----
    const int gcol  = col0 + (wc << 5) + l31;
    const int grow0 = row0 + (wr << 5);
    #pragma unroll
    for (int r = 0; r < 16; ++r) {
        const int rl = (r & 3) + ((r >> 2) << 3) + (l5 << 2);
        const int grow = grow0 + rl;
        const size_t idx = (size_t)grow * (size_t)ldo + gcol;
        const float p = acc[r];
        if (EPI == 0) {
            OutF[idx] = p;
        } else if (EPI == 1) {
            OutF[idx] = 0.2f * p;
        } else if (EPI == 2) {
            float x = (grow == gcol ? 1.0f : 0.0f) - 0.2f * p;
            unsigned short h, l; split2(x, h, l);
            OutHi[idx] = h; OutLo[idx] = l;
        } else {
            float x  = p + Cs[idx];
            float ax = fabsf(x) - LMDA;
            float y  = ax > 0.0f ? copysignf(ax, x) : 0.0f;
            unsigned short h, l; split2(y, h, l);
            OutHi[idx] = h; OutLo[idx] = l;
        }
    }
}

// fp32 -> (hi, lo) bf16 pair, elementwise
__global__ void k_split(const float* __restrict__ in, unsigned short* __restrict__ hi,
                        unsigned short* __restrict__ lo, int n)
{
    int i = blockIdx.x * 256 + threadIdx.x;
    if (i < n) {
        unsigned short h, l; split2(in[i], h, l);
        hi[i] = h; lo[i] = l;
    }
}

// R1 = soft_threshold(Cs) -> (hi, lo)
__global__ void k_ista0(const float* __restrict__ Cs, unsigned short* __restrict__ hi,
                        unsigned short* __restrict__ lo, int n)
{
    int i = blockIdx.x * 256 + threadIdx.x;
    if (i < n) {
        float x  = Cs[i];
        float ax = fabsf(x) - LMDA;
        float y  = ax > 0.0f ? copysignf(ax, x) : 0.0f;
        unsigned short h, l; split2(y, h, l);
        hi[i] = h; lo[i] = l;
    }
}

// Ut[j][k] = U[k][j], stored as bf16 pair. 32x32 LDS tile, padded.
__global__ __launch_bounds__(256)
void k_transpose_split(const float* __restrict__ in, unsigned short* __restrict__ hi,
                       unsigned short* __restrict__ lo)
{
    __shared__ float t[32][33];
    const int bx = blockIdx.x, by = blockIdx.y;
    const int lx = threadIdx.x & 31, ly = threadIdx.x >> 5;  // 32 x 8
    #pragma unroll
    for (int rr = 0; rr < 4; ++rr) {
        int r = ly * 4 + rr;
        t[r][lx] = in[(size_t)(by * 32 + r) * 1024 + bx * 32 + lx];
    }
    __syncthreads();
    #pragma unroll
    for (int rr = 0; rr < 4; ++rr) {
        int r = ly * 4 + rr;
        float v = t[lx][r];  // = in[by*32+lx][bx*32+r]
        unsigned short h, l; split2(v, h, l);
        size_t idx = (size_t)(bx * 32 + r) * 1024 + by * 32 + lx;
        hi[idx] = h; lo[idx] = l;
    }
}

extern "C" void kernel_launch(void* const* d_in, const int* in_sizes, int n_in,
                              void* d_out, int out_size, void* d_ws, size_t ws_size,
                              hipStream_t stream) {
    const float* img = (const float*)d_in[0];   // (2048, 1024) fp32
    const float* U   = (const float*)d_in[1];   // (1024, 1024) fp32
    float* out = (float*)d_out;                 // (2048, 1024) fp32

    const int B = 2048, K = 1024, M2 = 1024;
    const int EPOCHS = 150;

    char* ws = (char*)d_ws;
    auto MB = [](size_t m) { return m << 20; };
    unsigned short* Whi  = (unsigned short*)(ws + MB(0));    // 2 MB
    unsigned short* Wlo  = (unsigned short*)(ws + MB(2));    // 2 MB
    float*          Csc  = (float*)         (ws + MB(4));    // 8 MB  (0.2 * img @ U^T)
    unsigned short* Rahi = (unsigned short*)(ws + MB(12));   // 4 MB
    unsigned short* Ralo = (unsigned short*)(ws + MB(16));   // 4 MB
    unsigned short* Rbhi = (unsigned short*)(ws + MB(20));   // 4 MB (reused: img hi)
    unsigned short* Rblo = (unsigned short*)(ws + MB(24));   // 4 MB (reused: img lo)
    unsigned short* Uthi = (unsigned short*)(ws + MB(28));   // 2 MB
    unsigned short* Utlo = (unsigned short*)(ws + MB(30));   // 2 MB
    unsigned short* Uhi  = (unsigned short*)(ws + MB(32));   // 2 MB
    unsigned short* Ulo  = (unsigned short*)(ws + MB(34));   // 2 MB
    unsigned short* Ihi  = Rbhi;   // img splits only live until Csc is built
    unsigned short* Ilo  = Rblo;

    // ---- prologue ----
    k_split<<<dim3((K * M2) / 256), 256, 0, stream>>>(U, Uhi, Ulo, K * M2);
    k_split<<<dim3((B * M2) / 256), 256, 0, stream>>>(img, Ihi, Ilo, B * M2);
    k_transpose_split<<<dim3(32, 32), 256, 0, stream>>>(U, Uthi, Utlo);

    // W = I - 0.2 * U @ U^T   (1024x1024x1024)
    gemm_sp<2><<<dim3(16 * 16), 256, 0, stream>>>(Uhi, Ulo, M2, Uhi, Ulo, M2, M2, 16,
                                                  Whi, Wlo, nullptr, nullptr, K);
    // Csc = 0.2 * img @ U^T   (2048x1024x1024)
    gemm_sp<1><<<dim3(16 * 32), 256, 0, stream>>>(Ihi, Ilo, M2, Uhi, Ulo, M2, M2, 16,
                                                  nullptr, nullptr, Csc, nullptr, K);
    // R1 = st(Csc)  (iteration 1 of 150: R0 = 0 so P = 0)
    k_ista0<<<dim3((B * K) / 256), 256, 0, stream>>>(Csc, Rahi, Ralo, B * K);

    // ---- iterations 2..150: R <- st(R @ W + Csc) ----
    unsigned short *curh = Rahi, *curl = Ralo, *nxth = Rbhi, *nxtl = Rblo;
    for (int it = 0; it < EPOCHS - 1; ++it) {
        gemm_sp<3><<<dim3(16 * 32), 256, 0, stream>>>(curh, curl, K, Whi, Wlo, K, K, 16,
                                                      nxth, nxtl, nullptr, Csc, K);
        unsigned short* t;
        t = curh; curh = nxth; nxth = t;
        t = curl; curl = nxtl; nxtl = t;
    }

    // ---- out = R @ U  (NT against U^T) ----
    gemm_sp<0><<<dim3(16 * 32), 256, 0, stream>>>(curh, curl, K, Uthi, Utlo, K, K, 16,
                                                  nullptr, nullptr, out, nullptr, M2);
}

// Round 3
// 4631.028 us; speedup vs baseline: 2.5826x; 1.6529x over previous
//
#include <hip/hip_runtime.h>
#include <cstddef>
#include <cstdint>

using f32x4  = __attribute__((ext_vector_type(4))) float;
using bf16x8 = __attribute__((ext_vector_type(8))) short;
using u16x4  = __attribute__((ext_vector_type(4))) unsigned short;
typedef unsigned short u16;

#define LMDA 0.005f

__device__ __forceinline__ u16 f2bf(float f) {
    union { float f; uint32_t u; } v; v.f = f;
    return (u16)((v.u + 0x7FFFu + ((v.u >> 16) & 1u)) >> 16);
}
__device__ __forceinline__ float bf2f(u16 b) {
    union { uint32_t u; float f; } v; v.u = ((uint32_t)b) << 16;
    return v.f;
}
__device__ __forceinline__ void split2(float x, u16& h, u16& l) {
    h = f2bf(x); l = f2bf(x - bf2f(h));
}
__device__ __forceinline__ float sthr(float x) {
    float ax = fabsf(x) - LMDA;
    return ax > 0.0f ? copysignf(ax, x) : 0.0f;
}

// async 16B global -> LDS (HW writes lane l at ldsbase + l*16)
__device__ __forceinline__ void gload16(const u16* g, u16* l) {
    __builtin_amdgcn_global_load_lds(
        (const __attribute__((address_space(1))) unsigned int*)(const void*)g,
        (__attribute__((address_space(3))) unsigned int*)(void*)l, 16, 0, 0);
}

// ---------------------------------------------------------------------------
// Fused-3 split-bf16 NT GEMM, partial-K (split-K) producer.
//   P[chunk][m][n] = sum_{k in chunk} Ah*Bh + Al*Bh + Ah*Bl   (all bf16 pairs)
// Tile 128x128, 8 waves = 2(mr) x 2(nc) x 2(ks: k-slice of BK=64).
// mfma_f32_16x16x32_bf16, wavetile 64x64 = 4x4 frags, acc f32x4[4][4].
// LDS: 2 buffers x 64KB, fragment-ordered 1KB chunks (lane*16B => conflict-free
// ds_read_b128, and exactly global_load_lds' linear dest layout).
// 2-phase pipeline: stage(next) issued before compute(cur); vmcnt(0) drained
// only at end of step (T3-minimal recipe) so loads fly under the MFMAs.
// All matrices have k-stride 1024. N-stride of P is 1024.
// ---------------------------------------------------------------------------
__global__ __launch_bounds__(512, 2)
void gemm_f3(const u16* __restrict__ Ah, const u16* __restrict__ Al,
             const u16* __restrict__ Bh, const u16* __restrict__ Bl,
             int Mt, int Nt, int splitk,
             float* __restrict__ P, size_t pstride)
{
    __shared__ __align__(16) u16 S[2][64 * 512];   // 128 KiB

    // XCD-aware bijective swizzle (grids are multiples of 8)
    const int nwg = gridDim.x;
    const int fid = blockIdx.x;
    const int sid = (fid & 7) * (nwg >> 3) + (fid >> 3);
    const int ntile = Mt * Nt;
    const int tile  = sid % ntile;
    const int chunk = sid / ntile;
    const int row0 = (tile / Nt) << 7;
    const int col0 = (tile % Nt) << 7;

    const int tid  = threadIdx.x;
    const int lane = tid & 63;
    const int w    = tid >> 6;      // 0..7
    const int mr = w >> 2, nc = (w >> 1) & 1, ks = w & 1;

    // staging role: wave w owns chunks cs = w*8 + t (t=mi 0..7)
    //   cs bits: mat=cs>>5, h=(cs>>4)&1, kss=(cs>>3)&1, mi=cs&7
    // chunk(mat,h,kss,mi): lane l <- M[r0 + mi*16 + (l&15)][koff + kss*32 + (l>>4)*8 ..+8)
    const u16* sbase = (w >> 2) ? (((w >> 1) & 1) ? Bl : Bh)
                                : (((w >> 1) & 1) ? Al : Ah);
    const int  srow  = ((w >> 2) ? col0 : row0) + (lane & 15);
    const int  skb   = ((w & 1) << 5) + ((lane >> 4) << 3);

    auto stage = [&](int b, int koff) {
        const u16* g = sbase + (size_t)srow * 1024 + koff + skb;
        u16* d = &S[b][(w << 3) << 9];
        #pragma unroll
        for (int t = 0; t < 8; ++t)
            gload16(g + (size_t)(t << 4) * 1024, d + (t << 9));
    };

    f32x4 acc[4][4] = {};

    const int clen = 1024 / splitk;
    const int k0   = chunk * clen;
    const int nst  = clen >> 6;

    stage(0, k0);
    asm volatile("s_waitcnt vmcnt(0)" ::: "memory");
    __builtin_amdgcn_s_barrier();
    asm volatile("" ::: "memory");

    int cur = 0;
    for (int s = 0; s < nst; ++s) {
        if (s + 1 < nst) stage(cur ^ 1, k0 + ((s + 1) << 6));

        const u16* Sb = S[cur];
        const int abase = (ks << 3) + (mr << 2);         // A(h=0,ks,mr*4+i)
        const int bbase = 32 + (ks << 3) + (nc << 2);    // B(h=0,ks,nc*4+j)
        bf16x8 ah[4], al[4], bh[4], bl[4];
        #pragma unroll
        for (int i = 0; i < 4; ++i) {
            ah[i] = *(const bf16x8*)&Sb[(abase + i)      * 512 + (lane << 3)];
            al[i] = *(const bf16x8*)&Sb[(abase + 16 + i) * 512 + (lane << 3)];
            bh[i] = *(const bf16x8*)&Sb[(bbase + i)      * 512 + (lane << 3)];
            bl[i] = *(const bf16x8*)&Sb[(bbase + 16 + i) * 512 + (lane << 3)];
        }
        #pragma unroll
        for (int i = 0; i < 4; ++i)
            #pragma unroll
            for (int j = 0; j < 4; ++j)
                acc[i][j] = __builtin_amdgcn_mfma_f32_16x16x32_bf16(ah[i], bh[j], acc[i][j], 0, 0, 0);
        #pragma unroll
        for (int i = 0; i < 4; ++i)
            #pragma unroll
            for (int j = 0; j < 4; ++j)
                acc[i][j] = __builtin_amdgcn_mfma_f32_16x16x32_bf16(al[i], bh[j], acc[i][j], 0, 0, 0);
        #pragma unroll
        for (int i = 0; i < 4; ++i)
            #pragma unroll
            for (int j = 0; j < 4; ++j)
                acc[i][j] = __builtin_amdgcn_mfma_f32_16x16x32_bf16(ah[i], bl[j], acc[i][j], 0, 0, 0);

        asm volatile("s_waitcnt vmcnt(0)" ::: "memory");
        __builtin_amdgcn_s_barrier();
        asm volatile("" ::: "memory");
        cur ^= 1;
    }

    // ---- ks-reduce (2-way) via LDS, then partial store by ks==0 waves ----
    float* red = (float*)&S[0][0];            // 64KB needed, 128KB available
    const int at = ((mr << 1) + nc) * 64 + lane;
    if (ks == 1) {
        #pragma unroll
        for (int p = 0; p < 16; ++p)
            *(f32x4*)&red[(p * 256 + at) << 2] = acc[p >> 2][p & 3];
    }
    __syncthreads();
    if (ks == 0) {
        #pragma unroll
        for (int p = 0; p < 16; ++p)
            acc[p >> 2][p & 3] += *(const f32x4*)&red[(p * 256 + at) << 2];

        float* Pc = P + (size_t)chunk * pstride;
        const int gr0 = row0 + (mr << 6) + ((lane >> 4) << 2);
        const int gc  = col0 + (nc << 6) + (lane & 15);
        #pragma unroll
        for (int i = 0; i < 4; ++i)
            #pragma unroll
            for (int j = 0; j < 4; ++j)
                #pragma unroll
                for (int e = 0; e < 4; ++e)
                    Pc[(size_t)(gr0 + (i << 4) + e) * 1024 + gc + (j << 4)] = acc[i][j][e];
    }
}

// ---------------------------------------------------------------------------
// split-K reduce + fused epilogues (elementwise over n4 float4's)
// MODE 0: OutF = s                    (final out = R@U)
// MODE 1: OutF = 0.2s; OutH/L = split(st(0.2s))   (Csc and R1 together)
// MODE 2: OutH/L = split(I - 0.2s)    (W)
// MODE 3: OutH/L = split(st(s + Cs))  (ISTA step)
// ---------------------------------------------------------------------------
template<int MODE>
__global__ __launch_bounds__(256)
void k_reduce(const float* __restrict__ P, size_t pstride, int splitk, int n4,
              const float* __restrict__ Cs, float* __restrict__ OutF,
              u16* __restrict__ OutH, u16* __restrict__ OutL)
{
    int i = blockIdx.x * 256 + threadIdx.x;
    if (i >= n4) return;
    f32x4 s = *(const f32x4*)&P[(size_t)i << 2];
    for (int c = 1; c < splitk; ++c)
        s += *(const f32x4*)&P[(size_t)c * pstride + ((size_t)i << 2)];

    if (MODE == 0) {
        *(f32x4*)&OutF[(size_t)i << 2] = s;
    } else if (MODE == 1) {
        f32x4 f = 0.2f * s;
        *(f32x4*)&OutF[(size_t)i << 2] = f;
        u16x4 h, l;
        #pragma unroll
        for (int e = 0; e < 4; ++e) { u16 hh, ll; split2(sthr(f[e]), hh, ll); h[e] = hh; l[e] = ll; }
        *(u16x4*)&OutH[(size_t)i << 2] = h;
        *(u16x4*)&OutL[(size_t)i << 2] = l;
    } else if (MODE == 2) {
        const int r = (i << 2) >> 10;
        const int c0 = (i << 2) & 1023;
        u16x4 h, l;
        #pragma unroll
        for (int e = 0; e < 4; ++e) {
            float x = (r == c0 + e ? 1.0f : 0.0f) - 0.2f * s[e];
            u16 hh, ll; split2(x, hh, ll); h[e] = hh; l[e] = ll;
        }
        *(u16x4*)&OutH[(size_t)i << 2] = h;
        *(u16x4*)&OutL[(size_t)i << 2] = l;
    } else {
        f32x4 cs = *(const f32x4*)&Cs[(size_t)i << 2];
        u16x4 h, l;
        #pragma unroll
        for (int e = 0; e < 4; ++e) { u16 hh, ll; split2(sthr(s[e] + cs[e]), hh, ll); h[e] = hh; l[e] = ll; }
        *(u16x4*)&OutH[(size_t)i << 2] = h;
        *(u16x4*)&OutL[(size_t)i << 2] = l;
    }
}

// fp32 -> (hi, lo) bf16 pair, elementwise
__global__ void k_split(const float* __restrict__ in, u16* __restrict__ hi,
                        u16* __restrict__ lo, int n)
{
    int i = blockIdx.x * 256 + threadIdx.x;
    if (i < n) { u16 h, l; split2(in[i], h, l); hi[i] = h; lo[i] = l; }
}

// Ut[j][k] = U[k][j] as bf16 pair (32x32 LDS tile, padded)
__global__ __launch_bounds__(256)
void k_transpose_split(const float* __restrict__ in, u16* __restrict__ hi,
                       u16* __restrict__ lo)
{
    __shared__ float t[32][33];
    const int bx = blockIdx.x, by = blockIdx.y;
    const int lx = threadIdx.x & 31, ly = threadIdx.x >> 5;
    #pragma unroll
    for (int rr = 0; rr < 4; ++rr) {
        int r = ly * 4 + rr;
        t[r][lx] = in[(size_t)(by * 32 + r) * 1024 + bx * 32 + lx];
    }
    __syncthreads();
    #pragma unroll
    for (int rr = 0; rr < 4; ++rr) {
        int r = ly * 4 + rr;
        u16 h, l; split2(t[lx][r], h, l);
        size_t idx = (size_t)(bx * 32 + r) * 1024 + by * 32 + lx;
        hi[idx] = h; lo[idx] = l;
    }
}

extern "C" void kernel_launch(void* const* d_in, const int* in_sizes, int n_in,
                              void* d_out, int out_size, void* d_ws, size_t ws_size,
                              hipStream_t stream) {
    const float* img = (const float*)d_in[0];   // (2048, 1024) fp32
    const float* U   = (const float*)d_in[1];   // (1024, 1024) fp32
    float* out = (float*)d_out;                 // (2048, 1024) fp32

    char* ws = (char*)d_ws;
    auto MB = [](size_t m) { return m << 20; };
    u16*   Uh  = (u16*)(ws + MB(0));
    u16*   Ul  = (u16*)(ws + MB(2));
    u16*   Uth = (u16*)(ws + MB(4));
    u16*   Utl = (u16*)(ws + MB(6));
    u16*   Wh  = (u16*)(ws + MB(8));
    u16*   Wl  = (u16*)(ws + MB(10));
    float* Csc = (float*)(ws + MB(12));
    u16*   Rah = (u16*)(ws + MB(20));
    u16*   Ral = (u16*)(ws + MB(24));
    u16*   Rbh = (u16*)(ws + MB(28));
    u16*   Rbl = (u16*)(ws + MB(32));
    float* P   = (float*)(ws + MB(36));   // split-K partials: up to 2 x 8MB
    u16*   Ih  = Rbh;                     // img splits live only until Csc done
    u16*   Il  = Rbl;

    const int splitk = (ws_size >= MB(53)) ? 2 : 1;
    const size_t PS2 = (size_t)2048 * 1024;   // iteration-shaped partial stride
    const size_t PS1 = (size_t)1024 * 1024;   // W-shaped partial stride

    // ---- prologue ----
    k_split<<<4096, 256, 0, stream>>>(U, Uh, Ul, 1024 * 1024);
    k_split<<<8192, 256, 0, stream>>>(img, Ih, Il, 2048 * 1024);
    k_transpose_split<<<dim3(32, 32), 256, 0, stream>>>(U, Uth, Utl);

    // W = I - 0.2 * U @ U^T
    gemm_f3<<<64 * splitk, 512, 0, stream>>>(Uh, Ul, Uh, Ul, 8, 8, splitk, P, PS1);
    k_reduce<2><<<1024, 256, 0, stream>>>(P, PS1, splitk, 262144, nullptr, nullptr, Wh, Wl);

    // Csc = 0.2 * img @ U^T ; R1 = st(Csc)
    gemm_f3<<<128 * splitk, 512, 0, stream>>>(Ih, Il, Uh, Ul, 16, 8, splitk, P, PS2);
    k_reduce<1><<<2048, 256, 0, stream>>>(P, PS2, splitk, 524288, nullptr, Csc, Rah, Ral);

    // ---- iterations 2..150: R <- st(R @ W + Csc) ----
    u16 *ch = Rah, *cl = Ral, *nh = Rbh, *nl = Rbl;
    for (int it = 0; it < 149; ++it) {
        gemm_f3<<<128 * splitk, 512, 0, stream>>>(ch, cl, Wh, Wl, 16, 8, splitk, P, PS2);
        k_reduce<3><<<2048, 256, 0, stream>>>(P, PS2, splitk, 524288, Csc, nullptr, nh, nl);
        u16* t;
        t = ch; ch = nh; nh = t;
        t = cl; cl = nl; nl = t;
    }

    // ---- out = R @ U (NT against U^T) ----
    gemm_f3<<<128 * splitk, 512, 0, stream>>>(ch, cl, Uth, Utl, 16, 8, splitk, P, PS2);
    k_reduce<0><<<2048, 256, 0, stream>>>(P, PS2, splitk, 524288, nullptr, out, nullptr, nullptr);
}